// Round 5
// baseline (2952.327 us; speedup 1.0000x reference)
//
#include <hip/hip_runtime.h>

// ---------------------------------------------------------------------------
// WorldModelGRU (gfx950) — ROUND 11: fix r10's two LDS lo-plane read offsets.
// r10 ran (container OK -> r8/r9's global_load_lds variant implicated in the
// container deaths) but FAILED absmax 0.869: porting r8's 64x64 layout back
// to r7's 128x64 layout updated the lo-plane WRITES (4096+) but left two
// READS at r8's offset (2048+):
//   k_cell:  xl = lds[2048 + aoff]  -> must be lds[4096 + aoff]
//   k_outmm: al = lds[2048 + aoff]  -> must be lds[4096 + aoff]
// This round fixes exactly those two lines. Everything else is r10 =
// r7-proven structure + XCD-pinned 1-D block mapping (by = blockIdx.x & 7,
// each XCD's 64-col weight tile (786 KB) stays in its private L2).
// Arithmetic is BIT-IDENTICAL to the r7 PASS (absmax 0.001953125).
// ---------------------------------------------------------------------------

#define BB 4096
#define HH 512
#define TT 16
#define LL 3
#define BHs ((size_t)BB * HH)

typedef unsigned short u16;
typedef __attribute__((ext_vector_type(8))) short short8v;  // 8 bf16 (4 VGPR)
typedef __attribute__((ext_vector_type(4))) float f32x4;

#define MFMA16(a, b, c) __builtin_amdgcn_mfma_f32_16x16x32_bf16((a), (b), (c), 0, 0, 0)

__device__ __forceinline__ u16 f2bf(float x) {
    unsigned u = __float_as_uint(x);
    u += 0x7fffu + ((u >> 16) & 1u);          // RNE
    return (u16)(u >> 16);
}
__device__ __forceinline__ float bf2f(u16 h) {
    return __uint_as_float(((unsigned)h) << 16);
}
__device__ __forceinline__ float bf2f_s(short h) { return bf2f((u16)h); }

// ---------------------------------------------------------------------------
// fp32 -> (hi, lo) bf16 split, 4 elems/thread.
// ---------------------------------------------------------------------------
__global__ __launch_bounds__(256) void k_split(const float* __restrict__ src,
                                               u16* __restrict__ hi,
                                               u16* __restrict__ lo)
{
    size_t i = ((size_t)blockIdx.x * 256 + threadIdx.x) * 4;
    float4 v = *(const float4*)(src + i);
    float xs[4] = {v.x, v.y, v.z, v.w};
    u16 h4[4], l4[4];
    #pragma unroll
    for (int k = 0; k < 4; k++) {
        h4[k] = f2bf(xs[k]);
        l4[k] = f2bf(xs[k] - bf2f(h4[k]));
    }
    ushort4 hv; hv.x = h4[0]; hv.y = h4[1]; hv.z = h4[2]; hv.w = h4[3];
    ushort4 lv; lv.x = l4[0]; lv.y = l4[1]; lv.z = l4[2]; lv.w = l4[3];
    *(ushort4*)(hi + i) = hv;
    *(ushort4*)(lo + i) = lv;
}

// ---------------------------------------------------------------------------
// fp32 VALU GEMM — used ONCE for P = emb @ W_tp^T + b_tp (512x512x512).
// ---------------------------------------------------------------------------
__global__ __launch_bounds__(256) void v_gemm(
    const float* __restrict__ A,
    const float* __restrict__ W,
    const float* __restrict__ bias,
    float* __restrict__ out, long rstride)
{
    const int rowBase = blockIdx.x * 64;
    const int colBase = blockIdx.y * 64;
    const int tid = threadIdx.x;
    const int tx = tid & 15;
    const int ty = tid >> 4;

    __shared__ float As[64][17];
    __shared__ float Bs[64][17];

    float acc[4][4];
    #pragma unroll
    for (int r = 0; r < 4; r++)
        #pragma unroll
        for (int c = 0; c < 4; c++)
            acc[r][c] = 0.f;

    for (int k0 = 0; k0 < HH; k0 += 16) {
        int row = tid >> 2;
        int kb  = (tid & 3) * 4;
        const float4 va = *(const float4*)(A + (size_t)(rowBase + row) * HH + k0 + kb);
        const float4 vw = *(const float4*)(W + (size_t)(colBase + row) * HH + k0 + kb);
        As[row][kb + 0] = va.x; As[row][kb + 1] = va.y;
        As[row][kb + 2] = va.z; As[row][kb + 3] = va.w;
        Bs[row][kb + 0] = vw.x; Bs[row][kb + 1] = vw.y;
        Bs[row][kb + 2] = vw.z; Bs[row][kb + 3] = vw.w;
        __syncthreads();

        #pragma unroll
        for (int k = 0; k < 16; k++) {
            float a[4], w[4];
            #pragma unroll
            for (int r = 0; r < 4; r++) a[r] = As[ty * 4 + r][k];
            #pragma unroll
            for (int c = 0; c < 4; c++) w[c] = Bs[tx * 4 + c][k];
            #pragma unroll
            for (int r = 0; r < 4; r++)
                #pragma unroll
                for (int c = 0; c < 4; c++)
                    acc[r][c] += a[r] * w[c];
        }
        __syncthreads();
    }

    #pragma unroll
    for (int r = 0; r < 4; r++) {
        int b = rowBase + ty * 4 + r;
        #pragma unroll
        for (int c = 0; c < 4; c++) {
            int j = colBase + tx * 4 + c;
            out[(long)b * rstride + j] = acc[r][c] + bias[j];
        }
    }
}

// ---------------------------------------------------------------------------
// Fused split-bf16 MFMA GRU cell (r7-proven structure + XCD-pinned mapping).
// Tile: 128 batch rows x 64 H cols; grid 256 (1-D): bx = id>>3 (row tile),
// by = id&7 (col tile == XCD under round-robin dispatch). 512 thr = 8 waves
// (wr = wid>>2 row half, wc = wid&3 col quarter). Accumulators per wave:
// 4 gates (r,z,i_n,h_n) x 4 row-frags x f32x4. r/z accumulate BOTH X@Wih
// and Hp@Whh MFMAs.
// XMODE: 0 = X from hi/lo pair ptrs; 1 = X==0; 2 = X = P[gt];
//        3 = X = action @ W_a^T + b_a computed in staging.
// LDS (u16): X_hi[0,4096) X_lo[4096,8192) H_hi[8192) H_lo[12288)
//            W planes [16384 + p*2048), p = 0..11:
//            0..5 = {Wih_r,Wih_z,Wih_n,Whh_r,Whh_z,Whh_n} HI, 6..11 same LO.
// Tile row = 32 u16 (64 B); 16B chunks XOR-swizzled: ch ^= (row>>1)&3.
// ---------------------------------------------------------------------------
template <int XMODE>
__global__ __launch_bounds__(512, 2) void k_cell(
    const u16* __restrict__ Xhi, const u16* __restrict__ Xlo,
    const int* __restrict__ gt, int tok,
    const float* __restrict__ action, const float* __restrict__ W_a,
    const float* __restrict__ b_a,
    const u16* __restrict__ Wih_hi, const u16* __restrict__ Wih_lo,
    const u16* __restrict__ Whh_hi, const u16* __restrict__ Whh_lo,
    const float* __restrict__ bih, const float* __restrict__ bhh,
    const u16* __restrict__ Hin,   // pair: lo at +BHs
    u16* __restrict__ Hout)        // pair: lo at +BHs
{
    const int tid = threadIdx.x;
    const int lane = tid & 63;
    const int wid = tid >> 6;
    const int wr = wid >> 2;
    const int wc = wid & 3;
    const int bx = blockIdx.x >> 3;
    const int by = blockIdx.x & 7;            // XCD id under round-robin
    const int rowBase = bx * 128;
    const int colBase = by * 64;

    __shared__ u16 lds[40960];   // 80 KiB

    // ---- staging setup: X/H tiles = 128 rows x 4 chunks, 1 chunk/thread ----
    const int srow = tid >> 2;
    const int sch = tid & 3;
    const int xoff = srow * 32 + ((sch ^ ((srow >> 1) & 3)) * 8);

    const u16* xsrc_hi = nullptr;
    const u16* xsrc_lo = nullptr;
    if (XMODE == 0) {
        xsrc_hi = Xhi + (size_t)(rowBase + srow) * HH + sch * 8;
        xsrc_lo = Xlo + (size_t)(rowBase + srow) * HH + sch * 8;
    } else if (XMODE == 2) {
        size_t gr = (size_t)gt[(rowBase + srow) * TT + tok];
        xsrc_hi = Xhi + gr * HH + sch * 8;
        xsrc_lo = Xlo + gr * HH + sch * 8;
    }
    const u16* hsrc_hi = Hin + (size_t)(rowBase + srow) * HH + sch * 8;
    const u16* hsrc_lo = hsrc_hi + BHs;

    float a0 = 0.f, a1 = 0.f, a2 = 0.f;
    if (XMODE == 3) {
        a0 = action[(rowBase + srow) * 3 + 0];
        a1 = action[(rowBase + srow) * 3 + 1];
        a2 = action[(rowBase + srow) * 3 + 2];
    }

    // W staging: 12 planes x 256 chunks = 3072 chunks / 512 thr = 6 each
    const u16* wsrc[6];
    int wdst[6];
    #pragma unroll
    for (int i = 0; i < 6; i++) {
        int c = i * 512 + tid;
        int p = c >> 8;           // plane 0..11
        int q = c & 255;
        int j = q >> 2;           // block-local col 0..63
        int ch = q & 3;
        int phys = (p < 6) ? p : p - 6;
        int g = phys % 3;         // gate r/z/n
        const u16* base;
        if (p < 6) base = (phys < 3) ? Wih_hi : Whh_hi;
        else       base = (phys < 3) ? Wih_lo : Whh_lo;
        wsrc[i] = base + (size_t)(g * HH + colBase + j) * HH + ch * 8;
        wdst[i] = 16384 + p * 2048 + j * 32 + ((ch ^ ((j >> 1) & 3)) * 8);
    }

    // ---- fragment read offsets ----
    const int fcol = lane & 15;
    const int kg = lane >> 4;
    const int fj = wc * 16 + fcol;
    int woff[12];
    #pragma unroll
    for (int p = 0; p < 12; p++)
        woff[p] = 16384 + p * 2048 + fj * 32 + ((kg ^ ((fj >> 1) & 3)) * 8);
    int aoff[4];
    #pragma unroll
    for (int m = 0; m < 4; m++) {
        int r = wr * 64 + m * 16 + fcol;
        aoff[m] = r * 32 + ((kg ^ ((r >> 1) & 3)) * 8);
    }

    f32x4 accR[4], accZ[4], accNi[4], accNh[4];
    #pragma unroll
    for (int m = 0; m < 4; m++) {
        accR[m] = (f32x4){0.f, 0.f, 0.f, 0.f};
        accZ[m] = accR[m];
        accNi[m] = accR[m];
        accNh[m] = accR[m];
    }

    short8v rxh = {}, rxl = {}, rhh = {}, rhl = {}, rw[6];

    auto load_g = [&](int K0) {
        if (XMODE == 0 || XMODE == 2) {
            rxh = *(const short8v*)(xsrc_hi + K0);
            rxl = *(const short8v*)(xsrc_lo + K0);
        } else if (XMODE == 3) {
            short8v th, tl;
            #pragma unroll
            for (int kk = 0; kk < 8; kk++) {
                int k = K0 + sch * 8 + kk;
                float xv = a0 * W_a[k * 3 + 0] + a1 * W_a[k * 3 + 1] +
                           a2 * W_a[k * 3 + 2] + b_a[k];
                u16 hb = f2bf(xv);
                th[kk] = (short)hb;
                tl[kk] = (short)f2bf(xv - bf2f(hb));
            }
            rxh = th; rxl = tl;
        }
        rhh = *(const short8v*)(hsrc_hi + K0);
        rhl = *(const short8v*)(hsrc_lo + K0);
        #pragma unroll
        for (int i = 0; i < 6; i++) rw[i] = *(const short8v*)(wsrc[i] + K0);
    };
    auto write_l = [&]() {
        if (XMODE != 1) {
            *(short8v*)&lds[xoff] = rxh;
            *(short8v*)&lds[4096 + xoff] = rxl;
        }
        *(short8v*)&lds[8192 + xoff] = rhh;
        *(short8v*)&lds[12288 + xoff] = rhl;
        #pragma unroll
        for (int i = 0; i < 6; i++) *(short8v*)&lds[wdst[i]] = rw[i];
    };

    load_g(0);
    for (int k0 = 0; k0 < HH; k0 += 32) {
        if (k0) __syncthreads();
        write_l();
        __syncthreads();
        if (k0 + 32 < HH) load_g(k0 + 32);  // prefetch next tile over compute

        short8v wf[12];
        #pragma unroll
        for (int p = 0; p < 12; p++) wf[p] = *(const short8v*)&lds[woff[p]];
        #pragma unroll
        for (int m = 0; m < 4; m++) {
            short8v hh = *(const short8v*)&lds[8192 + aoff[m]];
            short8v hl = *(const short8v*)&lds[12288 + aoff[m]];
            accR[m]  = MFMA16(hh, wf[3],  accR[m]);
            accR[m]  = MFMA16(hh, wf[9],  accR[m]);
            accR[m]  = MFMA16(hl, wf[3],  accR[m]);
            accZ[m]  = MFMA16(hh, wf[4],  accZ[m]);
            accZ[m]  = MFMA16(hh, wf[10], accZ[m]);
            accZ[m]  = MFMA16(hl, wf[4],  accZ[m]);
            accNh[m] = MFMA16(hh, wf[5],  accNh[m]);
            accNh[m] = MFMA16(hh, wf[11], accNh[m]);
            accNh[m] = MFMA16(hl, wf[5],  accNh[m]);
            if (XMODE != 1) {
                short8v xh = *(const short8v*)&lds[aoff[m]];
                short8v xl = *(const short8v*)&lds[4096 + aoff[m]];   // FIXED (was 2048)
                accR[m]  = MFMA16(xh, wf[0], accR[m]);
                accR[m]  = MFMA16(xh, wf[6], accR[m]);
                accR[m]  = MFMA16(xl, wf[0], accR[m]);
                accZ[m]  = MFMA16(xh, wf[1], accZ[m]);
                accZ[m]  = MFMA16(xh, wf[7], accZ[m]);
                accZ[m]  = MFMA16(xl, wf[1], accZ[m]);
                accNi[m] = MFMA16(xh, wf[2], accNi[m]);
                accNi[m] = MFMA16(xh, wf[8], accNi[m]);
                accNi[m] = MFMA16(xl, wf[2], accNi[m]);
            }
        }
    }

    // ---- epilogue: GRU nonlinearity; C/D: col=lane&15, row=kg*4+reg ----
    const int j = colBase + fj;
    const float br  = bih[j] + bhh[j];
    const float bz  = bih[HH + j] + bhh[HH + j];
    const float bni = bih[2 * HH + j];
    const float bnh = bhh[2 * HH + j];
    #pragma unroll
    for (int m = 0; m < 4; m++) {
        #pragma unroll
        for (int r = 0; r < 4; r++) {
            int b = rowBase + wr * 64 + m * 16 + kg * 4 + r;
            size_t idx = (size_t)b * HH + j;
            float rr = 1.f / (1.f + __expf(-(accR[m][r] + br)));
            float zz = 1.f / (1.f + __expf(-(accZ[m][r] + bz)));
            float nn = tanhf(accNi[m][r] + bni + rr * (accNh[m][r] + bnh));
            float hp = bf2f(Hin[idx]) + bf2f(Hin[BHs + idx]);
            float h = (1.f - zz) * nn + zz * hp;
            u16 hb = f2bf(h);
            Hout[idx] = hb;
            Hout[BHs + idx] = f2bf(h - bf2f(hb));
        }
    }
}

// ---------------------------------------------------------------------------
// Split-bf16 MFMA GEMM for logits (r7-proven structure, XCD-pinned mapping).
// A = h pair [4096,512], W = [512,512] hi/lo. Tile 128x64, grid 256 (1-D),
// 8 waves. LDS (u16): A_hi[0) A_lo[4096) W_hi[8192) W_lo[10240), 24 KiB.
// ---------------------------------------------------------------------------
__global__ __launch_bounds__(512, 2) void k_outmm(
    const u16* __restrict__ Apair,
    const u16* __restrict__ Whi, const u16* __restrict__ Wlo,
    const float* __restrict__ bias,
    float* __restrict__ out, long rstride)
{
    const int tid = threadIdx.x;
    const int lane = tid & 63;
    const int wid = tid >> 6;
    const int wr = wid >> 2;
    const int wc = wid & 3;
    const int bx = blockIdx.x >> 3;
    const int by = blockIdx.x & 7;
    const int rowBase = bx * 128;
    const int colBase = by * 64;

    __shared__ u16 lds[12288];

    const int srow = tid >> 2;
    const int sch = tid & 3;
    const int aoff_s = srow * 32 + ((sch ^ ((srow >> 1) & 3)) * 8);
    const u16* asrc_h = Apair + (size_t)(rowBase + srow) * HH + sch * 8;
    const u16* asrc_l = asrc_h + BHs;

    const int wt = tid & 255;
    const int wjr = wt >> 2;
    const int wch = wt & 3;
    const u16* wsrc1 = ((tid < 256) ? Whi : Wlo) + (size_t)(colBase + wjr) * HH + wch * 8;
    const int wdst1 = ((tid < 256) ? 8192 : 10240) + wjr * 32 +
                      ((wch ^ ((wjr >> 1) & 3)) * 8);

    const int fcol = lane & 15;
    const int kg = lane >> 4;
    const int fj = wc * 16 + fcol;
    const int woff_h = 8192 + fj * 32 + ((kg ^ ((fj >> 1) & 3)) * 8);
    const int woff_l = woff_h + 2048;
    int aoff[4];
    #pragma unroll
    for (int m = 0; m < 4; m++) {
        int r = wr * 64 + m * 16 + fcol;
        aoff[m] = r * 32 + ((kg ^ ((r >> 1) & 3)) * 8);
    }

    f32x4 acc[4];
    #pragma unroll
    for (int m = 0; m < 4; m++) acc[m] = (f32x4){0.f, 0.f, 0.f, 0.f};

    short8v rah, ral, rwv;
    auto load_g = [&](int K0) {
        rah = *(const short8v*)(asrc_h + K0);
        ral = *(const short8v*)(asrc_l + K0);
        rwv = *(const short8v*)(wsrc1 + K0);
    };
    load_g(0);
    for (int k0 = 0; k0 < HH; k0 += 32) {
        if (k0) __syncthreads();
        *(short8v*)&lds[aoff_s] = rah;
        *(short8v*)&lds[4096 + aoff_s] = ral;
        *(short8v*)&lds[wdst1] = rwv;
        __syncthreads();
        if (k0 + 32 < HH) load_g(k0 + 32);

        short8v wfh = *(const short8v*)&lds[woff_h];
        short8v wfl = *(const short8v*)&lds[woff_l];
        #pragma unroll
        for (int m = 0; m < 4; m++) {
            short8v ah = *(const short8v*)&lds[aoff[m]];
            short8v al = *(const short8v*)&lds[4096 + aoff[m]];   // FIXED (was 2048)
            acc[m] = MFMA16(ah, wfh, acc[m]);
            acc[m] = MFMA16(ah, wfl, acc[m]);
            acc[m] = MFMA16(al, wfh, acc[m]);
        }
    }

    const int j = colBase + fj;
    const float bb = bias[j];
    #pragma unroll
    for (int m = 0; m < 4; m++) {
        #pragma unroll
        for (int r = 0; r < 4; r++) {
            int b = rowBase + wr * 64 + m * 16 + kg * 4 + r;
            out[(long)b * rstride + j] = acc[m][r] + bb;
        }
    }
}

// ---------------------------------------------------------------------------
// reward / done heads: one wave per batch row; h3 is a bf16 hi/lo pair.
// ---------------------------------------------------------------------------
__global__ __launch_bounds__(256) void k_heads(
    const u16* __restrict__ h3,
    const float* __restrict__ Wr, const float* __restrict__ br,
    const float* __restrict__ Wd, const float* __restrict__ bd,
    float* __restrict__ out_r, float* __restrict__ out_d)
{
    int wave = threadIdx.x >> 6;
    int lane = threadIdx.x & 63;
    int b = blockIdx.x * 4 + wave;
    const short8v vh = *(const short8v*)(h3 + (size_t)b * HH + lane * 8);
    const short8v vl = *(const short8v*)(h3 + BHs + (size_t)b * HH + lane * 8);
    float sr = 0.f, sd = 0.f;
    #pragma unroll
    for (int i = 0; i < 8; i++) {
        float hv = bf2f_s(vh[i]) + bf2f_s(vl[i]);
        sr += hv * Wr[lane * 8 + i];
        sd += hv * Wd[lane * 8 + i];
    }
    #pragma unroll
    for (int off = 32; off > 0; off >>= 1) {
        sr += __shfl_xor(sr, off, 64);
        sd += __shfl_xor(sd, off, 64);
    }
    if (lane == 0) {
        out_r[b] = sr + br[0];
        out_d[b] = sd + bd[0];
    }
}

// hi/lo pair -> fp32 (final hidden output), 8 elems/thread
__global__ __launch_bounds__(256) void k_fh(const u16* __restrict__ pair,
                                            float* __restrict__ out)
{
    size_t i = ((size_t)blockIdx.x * 256 + threadIdx.x) * 8;
    short8v h = *(const short8v*)(pair + i);
    short8v l = *(const short8v*)(pair + BHs + i);
    float4 o0, o1;
    o0.x = bf2f_s(h[0]) + bf2f_s(l[0]); o0.y = bf2f_s(h[1]) + bf2f_s(l[1]);
    o0.z = bf2f_s(h[2]) + bf2f_s(l[2]); o0.w = bf2f_s(h[3]) + bf2f_s(l[3]);
    o1.x = bf2f_s(h[4]) + bf2f_s(l[4]); o1.y = bf2f_s(h[5]) + bf2f_s(l[5]);
    o1.z = bf2f_s(h[6]) + bf2f_s(l[6]); o1.w = bf2f_s(h[7]) + bf2f_s(l[7]);
    *(float4*)(out + i) = o0;
    *(float4*)(out + i + 4) = o1;
}

// ---------------------------------------------------------------------------
extern "C" void kernel_launch(void* const* d_in, const int* in_sizes, int n_in,
                              void* d_out, int out_size, void* d_ws, size_t ws_size,
                              hipStream_t stream)
{
    const float* action      = (const float*)d_in[0];
    const float* prev_hidden = (const float*)d_in[1];
    const int*   gt          = (const int*)d_in[2];
    const float* W_a   = (const float*)d_in[3];
    const float* b_a   = (const float*)d_in[4];
    const float* emb   = (const float*)d_in[5];
    const float* W_tp  = (const float*)d_in[6];
    const float* b_tp  = (const float*)d_in[7];
    const float* W_ih  = (const float*)d_in[8];
    const float* W_hh  = (const float*)d_in[9];
    const float* b_ih  = (const float*)d_in[10];
    const float* b_hh  = (const float*)d_in[11];
    const float* W_out = (const float*)d_in[12];
    const float* b_out = (const float*)d_in[13];
    const float* W_r   = (const float*)d_in[14];
    const float* b_r   = (const float*)d_in[15];
    const float* W_d   = (const float*)d_in[16];
    const float* b_d   = (const float*)d_in[17];

    // ---- fp32 output layout (verified r6/r7) ----
    float* of       = (float*)d_out;
    float* o_logits = of;                          // B*T*C
    float* o_rew    = of + (size_t)BB * TT * 512;  // B
    float* o_done   = o_rew + BB;                  // B
    float* o_fh     = o_done + BB;                 // L*B*H

    // ---- workspace (u16 units): ~72.4 MB total (verified r7) ----
    const size_t NW = (size_t)LL * 3 * HH * HH;    // 2,359,296 per array
    const size_t WL = (size_t)3 * HH * HH;         // per-layer stride
    u16* ws      = (u16*)d_ws;
    u16* Wih_hi  = ws;
    u16* Wih_lo  = Wih_hi + NW;
    u16* Whh_hi  = Wih_lo + NW;
    u16* Whh_lo  = Whh_hi + NW;
    u16* Wout_hi = Whh_lo + NW;
    u16* Wout_lo = Wout_hi + (size_t)512 * 512;
    u16* P_hi    = Wout_lo + (size_t)512 * 512;
    u16* P_lo    = P_hi + (size_t)512 * 512;
    u16* hbase   = P_lo + (size_t)512 * 512;       // 6 pair buffers, 2*BH each
    float* Pf    = (float*)(hbase + (size_t)6 * 2 * BHs);  // 512x512 fp32 scratch

    auto hbuf = [&](int l, int par) -> u16* {
        return hbase + (size_t)(l * 2 + par) * 2 * BHs;
    };

    // ---- one-time per launch: weight splits, P table, prev_hidden split ----
    k_split<<<2304, 256, 0, stream>>>(W_ih, Wih_hi, Wih_lo);
    k_split<<<2304, 256, 0, stream>>>(W_hh, Whh_hi, Whh_lo);
    k_split<<<256, 256, 0, stream>>>(W_out, Wout_hi, Wout_lo);
    for (int l = 0; l < LL; l++)
        k_split<<<2048, 256, 0, stream>>>(prev_hidden + (size_t)l * BHs,
                                          hbuf(l, 0), hbuf(l, 0) + BHs);
    v_gemm<<<dim3(8, 8), 256, 0, stream>>>(emb, W_tp, b_tp, Pf, 512);
    k_split<<<256, 256, 0, stream>>>(Pf, P_hi, P_lo);

    // ---- 17 sequential GRU-stack steps ----
    for (int s = 0; s <= 16; s++) {
        const int pi = s & 1, po = pi ^ 1;
        for (int l = 0; l < LL; l++) {
            const u16* wihh = Wih_hi + (size_t)l * WL;
            const u16* wihl = Wih_lo + (size_t)l * WL;
            const u16* whhh = Whh_hi + (size_t)l * WL;
            const u16* whhl = Whh_lo + (size_t)l * WL;
            const float* bi = b_ih + (size_t)l * 3 * HH;
            const float* bh = b_hh + (size_t)l * 3 * HH;
            const u16* Hin = hbuf(l, pi);
            u16* Ho = hbuf(l, po);
            if (l > 0) {
                const u16* Xp = hbuf(l - 1, po);
                k_cell<0><<<256, 512, 0, stream>>>(Xp, Xp + BHs, nullptr, 0,
                    nullptr, nullptr, nullptr, wihh, wihl, whhh, whhl,
                    bi, bh, Hin, Ho);
            } else if (s == 0) {
                k_cell<3><<<256, 512, 0, stream>>>(nullptr, nullptr, nullptr, 0,
                    action, W_a, b_a, wihh, wihl, whhh, whhl, bi, bh, Hin, Ho);
            } else if (s == 1) {
                k_cell<1><<<256, 512, 0, stream>>>(nullptr, nullptr, nullptr, 0,
                    nullptr, nullptr, nullptr, wihh, wihl, whhh, whhl,
                    bi, bh, Hin, Ho);
            } else {
                k_cell<2><<<256, 512, 0, stream>>>(P_hi, P_lo, gt, s - 2,
                    nullptr, nullptr, nullptr, wihh, wihl, whhh, whhl,
                    bi, bh, Hin, Ho);
            }
        }
        if (s == 0) {
            k_heads<<<BB / 4, 256, 0, stream>>>(hbuf(2, po), W_r, b_r, W_d, b_d,
                                                o_rew, o_done);
        } else {
            k_outmm<<<256, 512, 0, stream>>>(hbuf(2, po), Wout_hi, Wout_lo, b_out,
                o_logits + (size_t)(s - 1) * 512, (long)TT * 512);
        }
    }

    // ---- final hidden stack (parity after s=16 is 1) -> fp32 output ----
    for (int l = 0; l < LL; l++)
        k_fh<<<1024, 256, 0, stream>>>(hbuf(l, 1), o_fh + (size_t)l * BHs);
}

// Round 6
// 2758.940 us; speedup vs baseline: 1.0701x; 1.0701x over previous
//
#include <hip/hip_runtime.h>

// ---------------------------------------------------------------------------
// WorldModelGRU (gfx950) — ROUND 12: layer-0 gate-precompute restructure.
// r11 PASSED (2952us, absmax 0.001953125) on a ~25% slower container (fill
// 96->121us). This round removes work algebraically:
//   gi(layer0, s>=2) = P[gt] @ Wih0^T = (P @ Wih0^T)[gt] = G0[gt]   (gather!)
//   gi(layer0, s==0) = action @ (Wih0 W_a)^T = action @ M0^T        (9 FLOP)
//   gi(layer0, s==1) = 0                                            (X = 0)
// => ALL 17 layer-0 cells become H-side-only MFMA (72->36 per wave-iter),
//    stage 6 W planes instead of 12, no X staging, LDS 80->40 KB.
// G0 built once by the proven 3-term split-bf16 GEMM (same math previously
// done in-cell); M0 in exact fp32. Layers 1-2 keep the r11-PASS XMODE0 path
// byte-identical. XCD-pinned mapping kept (by = blockIdx.x & 7).
// ---------------------------------------------------------------------------

#define BB 4096
#define HH 512
#define TT 16
#define LL 3
#define BHs ((size_t)BB * HH)

typedef unsigned short u16;
typedef __attribute__((ext_vector_type(8))) short short8v;  // 8 bf16 (4 VGPR)
typedef __attribute__((ext_vector_type(4))) float f32x4;

#define MFMA16(a, b, c) __builtin_amdgcn_mfma_f32_16x16x32_bf16((a), (b), (c), 0, 0, 0)

__device__ __forceinline__ u16 f2bf(float x) {
    unsigned u = __float_as_uint(x);
    u += 0x7fffu + ((u >> 16) & 1u);          // RNE
    return (u16)(u >> 16);
}
__device__ __forceinline__ float bf2f(u16 h) {
    return __uint_as_float(((unsigned)h) << 16);
}
__device__ __forceinline__ float bf2f_s(short h) { return bf2f((u16)h); }

// ---------------------------------------------------------------------------
// fp32 -> (hi, lo) bf16 split, 4 elems/thread.
// ---------------------------------------------------------------------------
__global__ __launch_bounds__(256) void k_split(const float* __restrict__ src,
                                               u16* __restrict__ hi,
                                               u16* __restrict__ lo)
{
    size_t i = ((size_t)blockIdx.x * 256 + threadIdx.x) * 4;
    float4 v = *(const float4*)(src + i);
    float xs[4] = {v.x, v.y, v.z, v.w};
    u16 h4[4], l4[4];
    #pragma unroll
    for (int k = 0; k < 4; k++) {
        h4[k] = f2bf(xs[k]);
        l4[k] = f2bf(xs[k] - bf2f(h4[k]));
    }
    ushort4 hv; hv.x = h4[0]; hv.y = h4[1]; hv.z = h4[2]; hv.w = h4[3];
    ushort4 lv; lv.x = l4[0]; lv.y = l4[1]; lv.z = l4[2]; lv.w = l4[3];
    *(ushort4*)(hi + i) = hv;
    *(ushort4*)(lo + i) = lv;
}

// ---------------------------------------------------------------------------
// fp32 VALU GEMM — used ONCE for P = emb @ W_tp^T + b_tp (512x512x512).
// ---------------------------------------------------------------------------
__global__ __launch_bounds__(256) void v_gemm(
    const float* __restrict__ A,
    const float* __restrict__ W,
    const float* __restrict__ bias,
    float* __restrict__ out, long rstride)
{
    const int rowBase = blockIdx.x * 64;
    const int colBase = blockIdx.y * 64;
    const int tid = threadIdx.x;
    const int tx = tid & 15;
    const int ty = tid >> 4;

    __shared__ float As[64][17];
    __shared__ float Bs[64][17];

    float acc[4][4];
    #pragma unroll
    for (int r = 0; r < 4; r++)
        #pragma unroll
        for (int c = 0; c < 4; c++)
            acc[r][c] = 0.f;

    for (int k0 = 0; k0 < HH; k0 += 16) {
        int row = tid >> 2;
        int kb  = (tid & 3) * 4;
        const float4 va = *(const float4*)(A + (size_t)(rowBase + row) * HH + k0 + kb);
        const float4 vw = *(const float4*)(W + (size_t)(colBase + row) * HH + k0 + kb);
        As[row][kb + 0] = va.x; As[row][kb + 1] = va.y;
        As[row][kb + 2] = va.z; As[row][kb + 3] = va.w;
        Bs[row][kb + 0] = vw.x; Bs[row][kb + 1] = vw.y;
        Bs[row][kb + 2] = vw.z; Bs[row][kb + 3] = vw.w;
        __syncthreads();

        #pragma unroll
        for (int k = 0; k < 16; k++) {
            float a[4], w[4];
            #pragma unroll
            for (int r = 0; r < 4; r++) a[r] = As[ty * 4 + r][k];
            #pragma unroll
            for (int c = 0; c < 4; c++) w[c] = Bs[tx * 4 + c][k];
            #pragma unroll
            for (int r = 0; r < 4; r++)
                #pragma unroll
                for (int c = 0; c < 4; c++)
                    acc[r][c] += a[r] * w[c];
        }
        __syncthreads();
    }

    #pragma unroll
    for (int r = 0; r < 4; r++) {
        int b = rowBase + ty * 4 + r;
        #pragma unroll
        for (int c = 0; c < 4; c++) {
            int j = colBase + tx * 4 + c;
            out[(long)b * rstride + j] = acc[r][c] + bias[j];
        }
    }
}

// M0 = Wih0 @ W_a  ([1536,3], exact fp32). grid 6 x 256.
__global__ __launch_bounds__(256) void k_m0(const float* __restrict__ Wih0,
                                            const float* __restrict__ W_a,
                                            float* __restrict__ M0)
{
    int jg = blockIdx.x * 256 + threadIdx.x;   // 0..1535
    float s0 = 0.f, s1 = 0.f, s2 = 0.f;
    for (int h = 0; h < HH; h++) {
        float w = Wih0[(size_t)jg * HH + h];
        s0 += w * W_a[h * 3 + 0];
        s1 += w * W_a[h * 3 + 1];
        s2 += w * W_a[h * 3 + 2];
    }
    M0[jg * 3 + 0] = s0;
    M0[jg * 3 + 1] = s1;
    M0[jg * 3 + 2] = s2;
}

// ---------------------------------------------------------------------------
// Fused split-bf16 MFMA GRU cell.
// XMODE 0 (layers 1,2): full path, BYTE-IDENTICAL to the r11 PASS.
//   LDS (u16, 80KB): X_hi[0) X_lo[4096) H_hi[8192) H_lo[12288)
//                    W planes [16384 + p*2048), p 0..11 (ih r,z,n | hh r,z,n; hi then lo).
// XMODE 1/4/5 (layer 0): H-side only (36 MFMA/wave-iter), 6 Whh planes,
//   LDS (u16, 40KB): H_hi[0) H_lo[4096) W planes [8192 + q*2048), q 0..5
//                    = {Whh_r,z,n} hi then lo.
//   Accumulator init: XMODE1 -> 0; XMODE4 -> G0[gt[b,tok]] gather;
//                     XMODE5 -> action[b] . M0 rows.
// Tile 128 rows x 64 cols; grid 256: bx = id>>3, by = id&7 (XCD-pinned).
// ---------------------------------------------------------------------------
template <int XMODE>
__global__ __launch_bounds__(512, 2) void k_cell(
    const u16* __restrict__ Xhi, const u16* __restrict__ Xlo,
    const int* __restrict__ gt, int tok,
    const float* __restrict__ action, const float* __restrict__ M0,
    const float* __restrict__ G0,
    const u16* __restrict__ Wih_hi, const u16* __restrict__ Wih_lo,
    const u16* __restrict__ Whh_hi, const u16* __restrict__ Whh_lo,
    const float* __restrict__ bih, const float* __restrict__ bhh,
    const u16* __restrict__ Hin,   // pair: lo at +BHs
    u16* __restrict__ Hout)        // pair: lo at +BHs
{
    constexpr bool FULL = (XMODE == 0);
    const int tid = threadIdx.x;
    const int lane = tid & 63;
    const int wid = tid >> 6;
    const int wr = wid >> 2;
    const int wc = wid & 3;
    const int bx = blockIdx.x >> 3;
    const int by = blockIdx.x & 7;            // XCD id under round-robin
    const int rowBase = bx * 128;
    const int colBase = by * 64;

    constexpr int HB0 = FULL ? 8192 : 0;
    constexpr int HB1 = FULL ? 12288 : 4096;
    constexpr int WB  = FULL ? 16384 : 8192;
    constexpr int NWP = FULL ? 12 : 6;        // staged W planes
    __shared__ u16 lds[FULL ? 40960 : 20480];

    // ---- staging setup: X/H tiles = 128 rows x 4 chunks, 1 chunk/thread ----
    const int srow = tid >> 2;
    const int sch = tid & 3;
    const int xoff = srow * 32 + ((sch ^ ((srow >> 1) & 3)) * 8);

    const u16* xsrc_hi = nullptr;
    const u16* xsrc_lo = nullptr;
    if (FULL) {
        xsrc_hi = Xhi + (size_t)(rowBase + srow) * HH + sch * 8;
        xsrc_lo = Xlo + (size_t)(rowBase + srow) * HH + sch * 8;
    }
    const u16* hsrc_hi = Hin + (size_t)(rowBase + srow) * HH + sch * 8;
    const u16* hsrc_lo = hsrc_hi + BHs;

    // W staging descriptors.
    constexpr int NWD = FULL ? 6 : 3;         // per-thread chunks
    const u16* wsrc[NWD];
    int wdst[NWD];
    #pragma unroll
    for (int i = 0; i < NWD; i++) {
        int c = i * 512 + tid;
        int p = c >> 8;           // plane index (12 or 6)
        int q = c & 255;
        int j2 = q >> 2;          // block-local col 0..63
        int ch = q & 3;
        const u16* base;
        int g;
        if (FULL) {
            int phys = (p < 6) ? p : p - 6;
            g = phys % 3;
            if (p < 6) base = (phys < 3) ? Wih_hi : Whh_hi;
            else       base = (phys < 3) ? Wih_lo : Whh_lo;
        } else {
            g = p % 3;
            base = (p < 3) ? Whh_hi : Whh_lo;
        }
        wsrc[i] = base + (size_t)(g * HH + colBase + j2) * HH + ch * 8;
        wdst[i] = WB + p * 2048 + j2 * 32 + ((ch ^ ((j2 >> 1) & 3)) * 8);
    }

    // ---- fragment read offsets ----
    const int fcol = lane & 15;
    const int kg = lane >> 4;
    const int fj = wc * 16 + fcol;
    const int j = colBase + fj;
    int woff[NWP];
    #pragma unroll
    for (int p = 0; p < NWP; p++)
        woff[p] = WB + p * 2048 + fj * 32 + ((kg ^ ((fj >> 1) & 3)) * 8);
    int aoff[4];
    #pragma unroll
    for (int m = 0; m < 4; m++) {
        int r = wr * 64 + m * 16 + fcol;
        aoff[m] = r * 32 + ((kg ^ ((r >> 1) & 3)) * 8);
    }

    f32x4 accR[4], accZ[4], accNi[4], accNh[4];
    #pragma unroll
    for (int m = 0; m < 4; m++) {
        accR[m] = (f32x4){0.f, 0.f, 0.f, 0.f};
        accZ[m] = accR[m];
        accNi[m] = accR[m];
        accNh[m] = accR[m];
    }

    // ---- layer-0 accumulator init: the precomputed X-side gates ----
    if constexpr (XMODE == 4) {
        #pragma unroll
        for (int m = 0; m < 4; m++) {
            #pragma unroll
            for (int r = 0; r < 4; r++) {
                int b = rowBase + wr * 64 + m * 16 + kg * 4 + r;
                int grow = gt[b * TT + tok];
                const float* g0r = G0 + (size_t)grow * 1536 + j;
                accR[m][r]  = g0r[0];
                accZ[m][r]  = g0r[512];
                accNi[m][r] = g0r[1024];
            }
        }
    } else if constexpr (XMODE == 5) {
        #pragma unroll
        for (int m = 0; m < 4; m++) {
            #pragma unroll
            for (int r = 0; r < 4; r++) {
                int b = rowBase + wr * 64 + m * 16 + kg * 4 + r;
                float a0 = action[b * 3 + 0];
                float a1 = action[b * 3 + 1];
                float a2 = action[b * 3 + 2];
                accR[m][r]  = a0 * M0[j * 3 + 0] + a1 * M0[j * 3 + 1] +
                              a2 * M0[j * 3 + 2];
                accZ[m][r]  = a0 * M0[(512 + j) * 3 + 0] + a1 * M0[(512 + j) * 3 + 1] +
                              a2 * M0[(512 + j) * 3 + 2];
                accNi[m][r] = a0 * M0[(1024 + j) * 3 + 0] + a1 * M0[(1024 + j) * 3 + 1] +
                              a2 * M0[(1024 + j) * 3 + 2];
            }
        }
    }

    short8v rxh = {}, rxl = {}, rhh = {}, rhl = {}, rw[NWD];

    auto load_g = [&](int K0) {
        if (FULL) {
            rxh = *(const short8v*)(xsrc_hi + K0);
            rxl = *(const short8v*)(xsrc_lo + K0);
        }
        rhh = *(const short8v*)(hsrc_hi + K0);
        rhl = *(const short8v*)(hsrc_lo + K0);
        #pragma unroll
        for (int i = 0; i < NWD; i++) rw[i] = *(const short8v*)(wsrc[i] + K0);
    };
    auto write_l = [&]() {
        if (FULL) {
            *(short8v*)&lds[xoff] = rxh;
            *(short8v*)&lds[4096 + xoff] = rxl;
        }
        *(short8v*)&lds[HB0 + xoff] = rhh;
        *(short8v*)&lds[HB1 + xoff] = rhl;
        #pragma unroll
        for (int i = 0; i < NWD; i++) *(short8v*)&lds[wdst[i]] = rw[i];
    };

    load_g(0);
    for (int k0 = 0; k0 < HH; k0 += 32) {
        if (k0) __syncthreads();
        write_l();
        __syncthreads();
        if (k0 + 32 < HH) load_g(k0 + 32);  // prefetch next tile over compute

        short8v wf[NWP];
        #pragma unroll
        for (int p = 0; p < NWP; p++) wf[p] = *(const short8v*)&lds[woff[p]];
        #pragma unroll
        for (int m = 0; m < 4; m++) {
            short8v hh = *(const short8v*)&lds[HB0 + aoff[m]];
            short8v hl = *(const short8v*)&lds[HB1 + aoff[m]];
            if constexpr (FULL) {
                accR[m]  = MFMA16(hh, wf[3],  accR[m]);
                accR[m]  = MFMA16(hh, wf[9],  accR[m]);
                accR[m]  = MFMA16(hl, wf[3],  accR[m]);
                accZ[m]  = MFMA16(hh, wf[4],  accZ[m]);
                accZ[m]  = MFMA16(hh, wf[10], accZ[m]);
                accZ[m]  = MFMA16(hl, wf[4],  accZ[m]);
                accNh[m] = MFMA16(hh, wf[5],  accNh[m]);
                accNh[m] = MFMA16(hh, wf[11], accNh[m]);
                accNh[m] = MFMA16(hl, wf[5],  accNh[m]);
                short8v xh = *(const short8v*)&lds[aoff[m]];
                short8v xl = *(const short8v*)&lds[4096 + aoff[m]];
                accR[m]  = MFMA16(xh, wf[0], accR[m]);
                accR[m]  = MFMA16(xh, wf[6], accR[m]);
                accR[m]  = MFMA16(xl, wf[0], accR[m]);
                accZ[m]  = MFMA16(xh, wf[1], accZ[m]);
                accZ[m]  = MFMA16(xh, wf[7], accZ[m]);
                accZ[m]  = MFMA16(xl, wf[1], accZ[m]);
                accNi[m] = MFMA16(xh, wf[2], accNi[m]);
                accNi[m] = MFMA16(xh, wf[8], accNi[m]);
                accNi[m] = MFMA16(xl, wf[2], accNi[m]);
            } else {
                // q: 0,1,2 = Whh r,z,n HI ; 3,4,5 = Whh r,z,n LO
                accR[m]  = MFMA16(hh, wf[0], accR[m]);
                accR[m]  = MFMA16(hh, wf[3], accR[m]);
                accR[m]  = MFMA16(hl, wf[0], accR[m]);
                accZ[m]  = MFMA16(hh, wf[1], accZ[m]);
                accZ[m]  = MFMA16(hh, wf[4], accZ[m]);
                accZ[m]  = MFMA16(hl, wf[1], accZ[m]);
                accNh[m] = MFMA16(hh, wf[2], accNh[m]);
                accNh[m] = MFMA16(hh, wf[5], accNh[m]);
                accNh[m] = MFMA16(hl, wf[2], accNh[m]);
            }
        }
    }

    // ---- epilogue: GRU nonlinearity; C/D: col=lane&15, row=kg*4+reg ----
    const float br  = bih[j] + bhh[j];
    const float bz  = bih[HH + j] + bhh[HH + j];
    const float bni = bih[2 * HH + j];
    const float bnh = bhh[2 * HH + j];
    #pragma unroll
    for (int m = 0; m < 4; m++) {
        #pragma unroll
        for (int r = 0; r < 4; r++) {
            int b = rowBase + wr * 64 + m * 16 + kg * 4 + r;
            size_t idx = (size_t)b * HH + j;
            float rr = 1.f / (1.f + __expf(-(accR[m][r] + br)));
            float zz = 1.f / (1.f + __expf(-(accZ[m][r] + bz)));
            float nn = tanhf(accNi[m][r] + bni + rr * (accNh[m][r] + bnh));
            float hp = bf2f(Hin[idx]) + bf2f(Hin[BHs + idx]);
            float h = (1.f - zz) * nn + zz * hp;
            u16 hb = f2bf(h);
            Hout[idx] = hb;
            Hout[BHs + idx] = f2bf(h - bf2f(hb));
        }
    }
}

// ---------------------------------------------------------------------------
// Split-bf16 MFMA GEMM for logits (r11 PASS, unchanged).
// ---------------------------------------------------------------------------
__global__ __launch_bounds__(512, 2) void k_outmm(
    const u16* __restrict__ Apair,
    const u16* __restrict__ Whi, const u16* __restrict__ Wlo,
    const float* __restrict__ bias,
    float* __restrict__ out, long rstride)
{
    const int tid = threadIdx.x;
    const int lane = tid & 63;
    const int wid = tid >> 6;
    const int wr = wid >> 2;
    const int wc = wid & 3;
    const int bx = blockIdx.x >> 3;
    const int by = blockIdx.x & 7;
    const int rowBase = bx * 128;
    const int colBase = by * 64;

    __shared__ u16 lds[12288];

    const int srow = tid >> 2;
    const int sch = tid & 3;
    const int aoff_s = srow * 32 + ((sch ^ ((srow >> 1) & 3)) * 8);
    const u16* asrc_h = Apair + (size_t)(rowBase + srow) * HH + sch * 8;
    const u16* asrc_l = asrc_h + BHs;

    const int wt = tid & 255;
    const int wjr = wt >> 2;
    const int wch = wt & 3;
    const u16* wsrc1 = ((tid < 256) ? Whi : Wlo) + (size_t)(colBase + wjr) * HH + wch * 8;
    const int wdst1 = ((tid < 256) ? 8192 : 10240) + wjr * 32 +
                      ((wch ^ ((wjr >> 1) & 3)) * 8);

    const int fcol = lane & 15;
    const int kg = lane >> 4;
    const int fj = wc * 16 + fcol;
    const int woff_h = 8192 + fj * 32 + ((kg ^ ((fj >> 1) & 3)) * 8);
    const int woff_l = woff_h + 2048;
    int aoff[4];
    #pragma unroll
    for (int m = 0; m < 4; m++) {
        int r = wr * 64 + m * 16 + fcol;
        aoff[m] = r * 32 + ((kg ^ ((r >> 1) & 3)) * 8);
    }

    f32x4 acc[4];
    #pragma unroll
    for (int m = 0; m < 4; m++) acc[m] = (f32x4){0.f, 0.f, 0.f, 0.f};

    short8v rah, ral, rwv;
    auto load_g = [&](int K0) {
        rah = *(const short8v*)(asrc_h + K0);
        ral = *(const short8v*)(asrc_l + K0);
        rwv = *(const short8v*)(wsrc1 + K0);
    };
    load_g(0);
    for (int k0 = 0; k0 < HH; k0 += 32) {
        if (k0) __syncthreads();
        *(short8v*)&lds[aoff_s] = rah;
        *(short8v*)&lds[4096 + aoff_s] = ral;
        *(short8v*)&lds[wdst1] = rwv;
        __syncthreads();
        if (k0 + 32 < HH) load_g(k0 + 32);

        short8v wfh = *(const short8v*)&lds[woff_h];
        short8v wfl = *(const short8v*)&lds[woff_l];
        #pragma unroll
        for (int m = 0; m < 4; m++) {
            short8v ah = *(const short8v*)&lds[aoff[m]];
            short8v al = *(const short8v*)&lds[4096 + aoff[m]];
            acc[m] = MFMA16(ah, wfh, acc[m]);
            acc[m] = MFMA16(ah, wfl, acc[m]);
            acc[m] = MFMA16(al, wfh, acc[m]);
        }
    }

    const int j = colBase + fj;
    const float bb = bias[j];
    #pragma unroll
    for (int m = 0; m < 4; m++) {
        #pragma unroll
        for (int r = 0; r < 4; r++) {
            int b = rowBase + wr * 64 + m * 16 + kg * 4 + r;
            out[(long)b * rstride + j] = acc[m][r] + bb;
        }
    }
}

// ---------------------------------------------------------------------------
// G0 = P @ Wih0^T (3-term split-bf16, fp32 out). A = P hi/lo [512,512],
// W = Wih0 hi/lo [1536,512]. Tile 128x64; grid 4*24 = 96 (bx = id/24,
// by = id%24). Same body as k_outmm modulo separate Alo ptr / no bias.
// ---------------------------------------------------------------------------
__global__ __launch_bounds__(512, 2) void k_g0(
    const u16* __restrict__ Ahi, const u16* __restrict__ Alo,
    const u16* __restrict__ Whi, const u16* __restrict__ Wlo,
    float* __restrict__ out, long rstride)
{
    const int tid = threadIdx.x;
    const int lane = tid & 63;
    const int wid = tid >> 6;
    const int wr = wid >> 2;
    const int wc = wid & 3;
    const int bx = blockIdx.x / 24;
    const int by = blockIdx.x % 24;
    const int rowBase = bx * 128;
    const int colBase = by * 64;

    __shared__ u16 lds[12288];

    const int srow = tid >> 2;
    const int sch = tid & 3;
    const int aoff_s = srow * 32 + ((sch ^ ((srow >> 1) & 3)) * 8);
    const u16* asrc_h = Ahi + (size_t)(rowBase + srow) * HH + sch * 8;
    const u16* asrc_l = Alo + (size_t)(rowBase + srow) * HH + sch * 8;

    const int wt = tid & 255;
    const int wjr = wt >> 2;
    const int wch = wt & 3;
    const u16* wsrc1 = ((tid < 256) ? Whi : Wlo) + (size_t)(colBase + wjr) * HH + wch * 8;
    const int wdst1 = ((tid < 256) ? 8192 : 10240) + wjr * 32 +
                      ((wch ^ ((wjr >> 1) & 3)) * 8);

    const int fcol = lane & 15;
    const int kg = lane >> 4;
    const int fj = wc * 16 + fcol;
    const int woff_h = 8192 + fj * 32 + ((kg ^ ((fj >> 1) & 3)) * 8);
    const int woff_l = woff_h + 2048;
    int aoff[4];
    #pragma unroll
    for (int m = 0; m < 4; m++) {
        int r = wr * 64 + m * 16 + fcol;
        aoff[m] = r * 32 + ((kg ^ ((r >> 1) & 3)) * 8);
    }

    f32x4 acc[4];
    #pragma unroll
    for (int m = 0; m < 4; m++) acc[m] = (f32x4){0.f, 0.f, 0.f, 0.f};

    short8v rah, ral, rwv;
    auto load_g = [&](int K0) {
        rah = *(const short8v*)(asrc_h + K0);
        ral = *(const short8v*)(asrc_l + K0);
        rwv = *(const short8v*)(wsrc1 + K0);
    };
    load_g(0);
    for (int k0 = 0; k0 < HH; k0 += 32) {
        if (k0) __syncthreads();
        *(short8v*)&lds[aoff_s] = rah;
        *(short8v*)&lds[4096 + aoff_s] = ral;
        *(short8v*)&lds[wdst1] = rwv;
        __syncthreads();
        if (k0 + 32 < HH) load_g(k0 + 32);

        short8v wfh = *(const short8v*)&lds[woff_h];
        short8v wfl = *(const short8v*)&lds[woff_l];
        #pragma unroll
        for (int m = 0; m < 4; m++) {
            short8v ah = *(const short8v*)&lds[aoff[m]];
            short8v al = *(const short8v*)&lds[4096 + aoff[m]];
            acc[m] = MFMA16(ah, wfh, acc[m]);
            acc[m] = MFMA16(ah, wfl, acc[m]);
            acc[m] = MFMA16(al, wfh, acc[m]);
        }
    }

    const int j = colBase + fj;
    #pragma unroll
    for (int m = 0; m < 4; m++) {
        #pragma unroll
        for (int r = 0; r < 4; r++) {
            int b = rowBase + wr * 64 + m * 16 + kg * 4 + r;
            out[(long)b * rstride + j] = acc[m][r];
        }
    }
}

// ---------------------------------------------------------------------------
// reward / done heads: one wave per batch row; h3 is a bf16 hi/lo pair.
// ---------------------------------------------------------------------------
__global__ __launch_bounds__(256) void k_heads(
    const u16* __restrict__ h3,
    const float* __restrict__ Wr, const float* __restrict__ br,
    const float* __restrict__ Wd, const float* __restrict__ bd,
    float* __restrict__ out_r, float* __restrict__ out_d)
{
    int wave = threadIdx.x >> 6;
    int lane = threadIdx.x & 63;
    int b = blockIdx.x * 4 + wave;
    const short8v vh = *(const short8v*)(h3 + (size_t)b * HH + lane * 8);
    const short8v vl = *(const short8v*)(h3 + BHs + (size_t)b * HH + lane * 8);
    float sr = 0.f, sd = 0.f;
    #pragma unroll
    for (int i = 0; i < 8; i++) {
        float hv = bf2f_s(vh[i]) + bf2f_s(vl[i]);
        sr += hv * Wr[lane * 8 + i];
        sd += hv * Wd[lane * 8 + i];
    }
    #pragma unroll
    for (int off = 32; off > 0; off >>= 1) {
        sr += __shfl_xor(sr, off, 64);
        sd += __shfl_xor(sd, off, 64);
    }
    if (lane == 0) {
        out_r[b] = sr + br[0];
        out_d[b] = sd + bd[0];
    }
}

// hi/lo pair -> fp32 (final hidden output), 8 elems/thread
__global__ __launch_bounds__(256) void k_fh(const u16* __restrict__ pair,
                                            float* __restrict__ out)
{
    size_t i = ((size_t)blockIdx.x * 256 + threadIdx.x) * 8;
    short8v h = *(const short8v*)(pair + i);
    short8v l = *(const short8v*)(pair + BHs + i);
    float4 o0, o1;
    o0.x = bf2f_s(h[0]) + bf2f_s(l[0]); o0.y = bf2f_s(h[1]) + bf2f_s(l[1]);
    o0.z = bf2f_s(h[2]) + bf2f_s(l[2]); o0.w = bf2f_s(h[3]) + bf2f_s(l[3]);
    o1.x = bf2f_s(h[4]) + bf2f_s(l[4]); o1.y = bf2f_s(h[5]) + bf2f_s(l[5]);
    o1.z = bf2f_s(h[6]) + bf2f_s(l[6]); o1.w = bf2f_s(h[7]) + bf2f_s(l[7]);
    *(float4*)(out + i) = o0;
    *(float4*)(out + i + 4) = o1;
}

// ---------------------------------------------------------------------------
extern "C" void kernel_launch(void* const* d_in, const int* in_sizes, int n_in,
                              void* d_out, int out_size, void* d_ws, size_t ws_size,
                              hipStream_t stream)
{
    const float* action      = (const float*)d_in[0];
    const float* prev_hidden = (const float*)d_in[1];
    const int*   gt          = (const int*)d_in[2];
    const float* W_a   = (const float*)d_in[3];
    const float* b_a   = (const float*)d_in[4];
    const float* emb   = (const float*)d_in[5];
    const float* W_tp  = (const float*)d_in[6];
    const float* b_tp  = (const float*)d_in[7];
    const float* W_ih  = (const float*)d_in[8];
    const float* W_hh  = (const float*)d_in[9];
    const float* b_ih  = (const float*)d_in[10];
    const float* b_hh  = (const float*)d_in[11];
    const float* W_out = (const float*)d_in[12];
    const float* b_out = (const float*)d_in[13];
    const float* W_r   = (const float*)d_in[14];
    const float* b_r   = (const float*)d_in[15];
    const float* W_d   = (const float*)d_in[16];
    const float* b_d   = (const float*)d_in[17];

    // ---- fp32 output layout (verified r6/r7/r11) ----
    float* of       = (float*)d_out;
    float* o_logits = of;                          // B*T*C
    float* o_rew    = of + (size_t)BB * TT * 512;  // B
    float* o_done   = o_rew + BB;                  // B
    float* o_fh     = o_done + BB;                 // L*B*H

    // ---- workspace (u16 units): exactly 75,497,472 B (r5-verified size) ----
    const size_t NW = (size_t)LL * 3 * HH * HH;    // 2,359,296 per array
    const size_t WL = (size_t)3 * HH * HH;         // per-layer stride
    u16* ws      = (u16*)d_ws;
    u16* Wih_hi  = ws;
    u16* Wih_lo  = Wih_hi + NW;
    u16* Whh_hi  = Wih_lo + NW;
    u16* Whh_lo  = Whh_hi + NW;
    u16* Wout_hi = Whh_lo + NW;
    u16* Wout_lo = Wout_hi + (size_t)512 * 512;
    u16* P_hi    = Wout_lo + (size_t)512 * 512;
    u16* P_lo    = P_hi + (size_t)512 * 512;
    u16* hbase   = P_lo + (size_t)512 * 512;       // 6 pair buffers, 2*BH each
    float* Pf    = (float*)(hbase + (size_t)6 * 2 * BHs);  // 512x512 fp32 scratch
    float* M0f   = Pf;                             // M0 [1536,3] — reuses Pf after split
    float* G0f   = Pf + (size_t)512 * 512;         // G0 [512,1536] fp32 (3 MB)

    auto hbuf = [&](int l, int par) -> u16* {
        return hbase + (size_t)(l * 2 + par) * 2 * BHs;
    };

    // ---- one-time: weight splits, P, M0, G0, prev_hidden split ----
    k_split<<<2304, 256, 0, stream>>>(W_ih, Wih_hi, Wih_lo);
    k_split<<<2304, 256, 0, stream>>>(W_hh, Whh_hi, Whh_lo);
    k_split<<<256, 256, 0, stream>>>(W_out, Wout_hi, Wout_lo);
    for (int l = 0; l < LL; l++)
        k_split<<<2048, 256, 0, stream>>>(prev_hidden + (size_t)l * BHs,
                                          hbuf(l, 0), hbuf(l, 0) + BHs);
    v_gemm<<<dim3(8, 8), 256, 0, stream>>>(emb, W_tp, b_tp, Pf, 512);
    k_split<<<256, 256, 0, stream>>>(Pf, P_hi, P_lo);
    k_m0<<<6, 256, 0, stream>>>(W_ih, W_a, M0f);   // after k_split consumed Pf
    k_g0<<<96, 512, 0, stream>>>(P_hi, P_lo, Wih_hi, Wih_lo, G0f, 1536);

    // ---- 17 sequential GRU-stack steps ----
    for (int s = 0; s <= 16; s++) {
        const int pi = s & 1, po = pi ^ 1;
        for (int l = 0; l < LL; l++) {
            const u16* wihh = Wih_hi + (size_t)l * WL;
            const u16* wihl = Wih_lo + (size_t)l * WL;
            const u16* whhh = Whh_hi + (size_t)l * WL;
            const u16* whhl = Whh_lo + (size_t)l * WL;
            const float* bi = b_ih + (size_t)l * 3 * HH;
            const float* bh = b_hh + (size_t)l * 3 * HH;
            const u16* Hin = hbuf(l, pi);
            u16* Ho = hbuf(l, po);
            if (l > 0) {
                const u16* Xp = hbuf(l - 1, po);
                k_cell<0><<<256, 512, 0, stream>>>(Xp, Xp + BHs, nullptr, 0,
                    nullptr, nullptr, nullptr, wihh, wihl, whhh, whhl,
                    bi, bh, Hin, Ho);
            } else if (s == 0) {
                k_cell<5><<<256, 512, 0, stream>>>(nullptr, nullptr, nullptr, 0,
                    action, M0f, nullptr, wihh, wihl, whhh, whhl, bi, bh, Hin, Ho);
            } else if (s == 1) {
                k_cell<1><<<256, 512, 0, stream>>>(nullptr, nullptr, nullptr, 0,
                    nullptr, nullptr, nullptr, wihh, wihl, whhh, whhl,
                    bi, bh, Hin, Ho);
            } else {
                k_cell<4><<<256, 512, 0, stream>>>(nullptr, nullptr, gt, s - 2,
                    nullptr, nullptr, G0f, wihh, wihl, whhh, whhl,
                    bi, bh, Hin, Ho);
            }
        }
        if (s == 0) {
            k_heads<<<BB / 4, 256, 0, stream>>>(hbuf(2, po), W_r, b_r, W_d, b_d,
                                                o_rew, o_done);
        } else {
            k_outmm<<<256, 512, 0, stream>>>(hbuf(2, po), Wout_hi, Wout_lo, b_out,
                o_logits + (size_t)(s - 1) * 512, (long)TT * 512);
        }
    }

    // ---- final hidden stack (parity after s=16 is 1) -> fp32 output ----
    for (int l = 0; l < LL; l++)
        k_fh<<<1024, 256, 0, stream>>>(hbuf(l, 1), o_fh + (size_t)l * BHs);
}